// Round 4
// baseline (114.528 us; speedup 1.0000x reference)
//
#include <hip/hip_runtime.h>
#include <math.h>

#define T 8192
#define D 36
#define NCH 64
#define CHUNK (T / NCH)             // 128
#define RPT 8                       // rows per thread in scan
#define ROWS_PER_BLOCK (256 * RPT)  // 2048
#define RBLK (T / ROWS_PER_BLOCK)   // 4

// ws layout (floats):
// [0, 2T*NCH)                     pv   (chunk-major: pv[c*2T + prow])
// [2T*NCH, 2T*NCH+4T)             Kg   (float2: Kg[head*T + j])
// [2T*NCH+4T, 2T*NCH+8T)          Qg   (float2: Qg[head*T + row])

__device__ __forceinline__ void load_row(const float* __restrict__ E, int j,
                                         float* e) {
    // row byte offset = j*144, 16B aligned -> 9 float4 loads
    const float4* Er = (const float4*)(E + j * D);
#pragma unroll
    for (int i = 0; i < D / 4; ++i) {
        float4 v = Er[i];
        e[4 * i + 0] = v.x;
        e[4 * i + 1] = v.y;
        e[4 * i + 2] = v.z;
        e[4 * i + 3] = v.w;
    }
}

// Fused Q/K-projection + max-only scan. grid (RBLK=4, NCH=64, 2), block 256.
// Every block computes its own K-chunk (128 rows, half the threads) and its
// own 8 q-rows per thread directly from E (L2-resident). All projections use
// the identical d-ascending fmaf chain => bit-identical across blocks, so the
// designated writer blocks persist exactly the bits the scanners consumed,
// and finalize's equality search reproduces the argmax exactly.
// Scan cost/wave ~6144 cyc; fused q-proj adds ~1152 (~19%), K-proj ~144.
__global__ __launch_bounds__(256) void scanfused(
    const float* __restrict__ E,
    const float* __restrict__ WQp, const float* __restrict__ WKp,
    const float* __restrict__ WQs, const float* __restrict__ WKs,
    float* __restrict__ pv, float2* __restrict__ Kg, float2* __restrict__ Qg) {
    const int head = blockIdx.z;
    const float* __restrict__ WQ = head ? WQs : WQp;
    const float* __restrict__ WK = head ? WKs : WKp;

    __shared__ float2 sk[CHUNK];
    const int j0 = blockIdx.y * CHUNK;

    // --- K chunk: threads 0..127 project one row each ---
    if (threadIdx.x < CHUNK) {
        const int j = j0 + threadIdx.x;
        float e[D];
        load_row(E, j, e);
        float k0 = 0.f, k1 = 0.f;
#pragma unroll
        for (int d = 0; d < D; ++d) {
            k0 = fmaf(e[d], WK[d], k0);
            k1 = fmaf(e[d], WK[D + d], k1);
        }
        float2 kk = make_float2(k0, k1);
        sk[threadIdx.x] = kk;
        if (blockIdx.x == 0) Kg[head * T + j] = kk;  // bit-exact K for finalize
    }

    // --- own 8 q-rows in registers (same chain => bit-identical) ---
    const int row0 = blockIdx.x * ROWS_PER_BLOCK;
    float2 q[RPT];
#pragma unroll
    for (int i = 0; i < RPT; ++i) {
        const int row = row0 + i * 256 + threadIdx.x;
        float e[D];
        load_row(E, row, e);
        float q0 = 0.f, q1 = 0.f;
#pragma unroll
        for (int d = 0; d < D; ++d) {
            q0 = fmaf(e[d], WQ[d], q0);
            q1 = fmaf(e[d], WQ[D + d], q1);
        }
        q[i] = make_float2(q0, q1);
    }
    if (blockIdx.y == 0) {
#pragma unroll
        for (int i = 0; i < RPT; ++i)
            Qg[head * T + row0 + i * 256 + threadIdx.x] = q[i];
    }
    __syncthreads();

    // --- max-only scan: one wave-uniform ds_read_b128 feeds 16 score updates ---
    float best[RPT];
#pragma unroll
    for (int i = 0; i < RPT; ++i) best[i] = -INFINITY;

    const float4* sk4 = (const float4*)sk;
#pragma unroll 8
    for (int k = 0; k < CHUNK / 2; ++k) {
        float4 kk = sk4[k];  // K[2k], K[2k+1] broadcast
#pragma unroll
        for (int i = 0; i < RPT; ++i) {
            float s0 = fmaf(q[i].x, kk.x, q[i].y * kk.y);  // identical expr
            float s1 = fmaf(q[i].x, kk.z, q[i].y * kk.w);
            best[i] = fmaxf(best[i], fmaxf(s0, s1));  // exact max, order-free
        }
    }
    const int base = blockIdx.y * 2 * T + head * T + row0 + threadIdx.x;
#pragma unroll
    for (int i = 0; i < RPT; ++i) pv[base + i * 256] = best[i];  // coalesced
}

// One wave per row (validated in round 3, absmax=0): butterfly-max the 64
// chunk maxima, pick the lowest winning chunk, first-occurrence equality
// search within its 128 elements (bit-exact recompute), then V[bi] with the
// sequential d-ascending fmaf chain.
__global__ __launch_bounds__(256) void finalize(
    const float* __restrict__ E,
    const float* __restrict__ WVop, const float* __restrict__ WVarg,
    const float* __restrict__ WVs,
    const float* __restrict__ pv, const float2* __restrict__ Qg,
    const float2* __restrict__ Kg, float* __restrict__ out) {
    const int wid = threadIdx.x >> 6;
    const int lane = threadIdx.x & 63;
    const int prow = blockIdx.x * 4 + wid;  // 0 .. 2T-1
    const int head = prow >> 13;
    const int row = prow & (T - 1);

    const float v = pv[lane * 2 * T + prow];  // lane == chunk index
    float m = v;
#pragma unroll
    for (int off = 32; off; off >>= 1) m = fmaxf(m, __shfl_xor(m, off));
    // lowest chunk holding the max => first occurrence across chunks
    const unsigned long long cb = __ballot(v == m);
    const int cwin = __ffsll(cb) - 1;

    const float2 q = Qg[prow];
    int bi;
    {
        int j = head * T + cwin * CHUNK + lane;
        float2 kk = Kg[j];
        float s = fmaf(q.x, kk.x, q.y * kk.y);  // bit-identical expression
        unsigned long long eb = __ballot(s == m);
        if (eb) {
            bi = cwin * CHUNK + __ffsll(eb) - 1;
        } else {  // guaranteed hit in second half
            kk = Kg[j + 64];
            s = fmaf(q.x, kk.x, q.y * kk.y);
            eb = __ballot(s == m);
            bi = cwin * CHUNK + 64 + __ffsll(eb) - 1;
        }
    }

    float e[D];
    load_row(E, bi, e);  // broadcast load, E is L2-resident
    if (head == 0) {
        float vop = 0.f, varg = 0.f;
#pragma unroll
        for (int d = 0; d < D; ++d) {
            vop = fmaf(e[d], WVop[d], vop);
            varg = fmaf(e[d], WVarg[d], varg);
        }
        if (lane == 0) {
            out[row] = vop;
            out[T + row] = varg;
        }
    } else {
        float vs = 0.f;
#pragma unroll
        for (int d = 0; d < D; ++d) vs = fmaf(e[d], WVs[d], vs);
        if (lane == 0) out[2 * T + row] = vs;
    }
}

extern "C" void kernel_launch(void* const* d_in, const int* in_sizes, int n_in,
                              void* d_out, int out_size, void* d_ws,
                              size_t ws_size, hipStream_t stream) {
    const float* E = (const float*)d_in[0];
    const float* WQp = (const float*)d_in[1];
    const float* WKp = (const float*)d_in[2];
    const float* WVop = (const float*)d_in[3];
    const float* WVarg = (const float*)d_in[4];
    const float* WQs = (const float*)d_in[5];
    const float* WKs = (const float*)d_in[6];
    const float* WVs = (const float*)d_in[7];
    float* out = (float*)d_out;

    float* wsf = (float*)d_ws;
    float* pv = wsf;
    float2* Kg = (float2*)(wsf + 2 * T * NCH);
    float2* Qg = (float2*)(wsf + 2 * T * NCH + 4 * T);

    dim3 gA(RBLK, NCH, 2);
    scanfused<<<gA, 256, 0, stream>>>(E, WQp, WKp, WQs, WKs, pv, Kg, Qg);

    finalize<<<(2 * T) / 4, 256, 0, stream>>>(E, WVop, WVarg, WVs, pv, Qg, Kg,
                                              out);
}

// Round 5
// 93.798 us; speedup vs baseline: 1.2210x; 1.2210x over previous
//
#include <hip/hip_runtime.h>
#include <math.h>

#define T 8192
#define D 36
#define NCH 64
#define CHUNK (T / NCH)             // 128
#define RPT 8                       // rows per thread in scan
#define ROWS_PER_BLOCK (256 * RPT)  // 2048
#define RBLK (T / ROWS_PER_BLOCK)   // 4

// ws layout (floats):
// [0, 2T*NCH)                     pv   (chunk-major: pv[c*2T + prow])
// [2T*NCH, 2T*NCH+4T)             Kg   (float2: Kg[head*T + j])
// [2T*NCH+4T, 2T*NCH+8T)          Qg   (float2: Qg[head*T + row])
//
// Structure note (round-4 lesson): do NOT fuse the Q projection into the
// scan. Re-deriving Q per scan block = 72 latency-bound global loads per
// thread at 2 waves/SIMD (~+18 us). Separate proj pays E-read latency once.

__device__ __forceinline__ void load_row(const float* __restrict__ E, int j,
                                         float* e) {
    // row byte offset = j*144, 16B aligned -> 9 float4 loads
    const float4* Er = (const float4*)(E + j * D);
#pragma unroll
    for (int i = 0; i < D / 4; ++i) {
        float4 v = Er[i];
        e[4 * i + 0] = v.x;
        e[4 * i + 1] = v.y;
        e[4 * i + 2] = v.z;
        e[4 * i + 3] = v.w;
    }
}

// Kernel A: Q/K projections for both heads (d-ascending fmaf chains, bit-exact
// vs the validated rounds). T threads.
__global__ __launch_bounds__(256) void proj_qk(
    const float* __restrict__ E,
    const float* __restrict__ WQp, const float* __restrict__ WKp,
    const float* __restrict__ WQs, const float* __restrict__ WKs,
    float2* __restrict__ Qg, float2* __restrict__ Kg) {
    const int t = blockIdx.x * 256 + threadIdx.x;
    float e[D];
    load_row(E, t, e);
    float qp0 = 0.f, qp1 = 0.f, kp0 = 0.f, kp1 = 0.f;
    float qs0 = 0.f, qs1 = 0.f, ks0 = 0.f, ks1 = 0.f;
#pragma unroll
    for (int d = 0; d < D; ++d) {
        float ed = e[d];
        qp0 = fmaf(ed, WQp[d], qp0);
        qp1 = fmaf(ed, WQp[D + d], qp1);
        kp0 = fmaf(ed, WKp[d], kp0);
        kp1 = fmaf(ed, WKp[D + d], kp1);
        qs0 = fmaf(ed, WQs[d], qs0);
        qs1 = fmaf(ed, WQs[D + d], qs1);
        ks0 = fmaf(ed, WKs[d], ks0);
        ks1 = fmaf(ed, WKs[D + d], ks1);
    }
    Qg[t] = make_float2(qp0, qp1);
    Qg[T + t] = make_float2(qs0, qs1);
    Kg[t] = make_float2(kp0, kp1);
    Kg[T + t] = make_float2(ks0, ks1);
}

// Kernel B: max-only scan with 8-row blocking. One wave-uniform ds_read_b128
// (2 K-pairs) feeds 16 score updates -> LDS-issue is off the critical path;
// VALU-bound at ~3 VALU/score. grid (RBLK=4, NCH=64, 2), block 256.
__global__ __launch_bounds__(256) void maxscan(
    const float2* __restrict__ Qg, const float2* __restrict__ Kg,
    float* __restrict__ pv) {
    const int head = blockIdx.z;
    const int row0 = blockIdx.x * ROWS_PER_BLOCK;
    const int j0 = blockIdx.y * CHUNK;

    __shared__ float4 sk4[CHUNK / 2];
    if (threadIdx.x < CHUNK)
        ((float2*)sk4)[threadIdx.x] = Kg[head * T + j0 + threadIdx.x];

    float2 q[RPT];
#pragma unroll
    for (int i = 0; i < RPT; ++i)
        q[i] = Qg[head * T + row0 + i * 256 + threadIdx.x];
    __syncthreads();

    float best[RPT];
#pragma unroll
    for (int i = 0; i < RPT; ++i) best[i] = -INFINITY;

#pragma unroll 8
    for (int k = 0; k < CHUNK / 2; ++k) {
        float4 kk = sk4[k];  // K[2k], K[2k+1] (wave-uniform broadcast read)
#pragma unroll
        for (int i = 0; i < RPT; ++i) {
            float s0 = fmaf(q[i].x, kk.x, q[i].y * kk.y);  // identical expr
            float s1 = fmaf(q[i].x, kk.z, q[i].y * kk.w);
            best[i] = fmaxf(best[i], fmaxf(s0, s1));  // exact max, order-free
        }
    }
    const int base = blockIdx.y * 2 * T + head * T + row0 + threadIdx.x;
#pragma unroll
    for (int i = 0; i < RPT; ++i) pv[base + i * 256] = best[i];  // coalesced
}

// Kernel C: one wave per row. 64 lanes = 64 chunk maxima, butterfly max,
// lowest winning chunk, first-occurrence equality search within the winning
// 128-element chunk (bit-exact recompute), then V[bi] via the sequential
// d-ascending fmaf chain.
__global__ __launch_bounds__(256) void finalize(
    const float* __restrict__ E,
    const float* __restrict__ WVop, const float* __restrict__ WVarg,
    const float* __restrict__ WVs,
    const float* __restrict__ pv, const float2* __restrict__ Qg,
    const float2* __restrict__ Kg, float* __restrict__ out) {
    const int wid = threadIdx.x >> 6;
    const int lane = threadIdx.x & 63;
    const int prow = blockIdx.x * 4 + wid;  // 0 .. 2T-1
    const int head = prow >> 13;
    const int row = prow & (T - 1);

    const float v = pv[lane * 2 * T + prow];  // lane == chunk index
    float m = v;
#pragma unroll
    for (int off = 32; off; off >>= 1) m = fmaxf(m, __shfl_xor(m, off));
    // lowest chunk holding the max => first occurrence across chunks
    const unsigned long long cb = __ballot(v == m);
    const int cwin = __ffsll(cb) - 1;

    const float2 q = Qg[prow];
    int bi;
    {
        int j = head * T + cwin * CHUNK + lane;
        float2 kk = Kg[j];
        float s = fmaf(q.x, kk.x, q.y * kk.y);  // bit-identical expression
        unsigned long long eb = __ballot(s == m);
        if (eb) {
            bi = cwin * CHUNK + __ffsll(eb) - 1;
        } else {  // guaranteed hit in second half
            kk = Kg[j + 64];
            s = fmaf(q.x, kk.x, q.y * kk.y);
            eb = __ballot(s == m);
            bi = cwin * CHUNK + 64 + __ffsll(eb) - 1;
        }
    }

    float e[D];
    load_row(E, bi, e);  // broadcast load, E is L2-resident
    if (head == 0) {
        float vop = 0.f, varg = 0.f;
#pragma unroll
        for (int d = 0; d < D; ++d) {
            vop = fmaf(e[d], WVop[d], vop);
            varg = fmaf(e[d], WVarg[d], varg);
        }
        if (lane == 0) {
            out[row] = vop;
            out[T + row] = varg;
        }
    } else {
        float vs = 0.f;
#pragma unroll
        for (int d = 0; d < D; ++d) vs = fmaf(e[d], WVs[d], vs);
        if (lane == 0) out[2 * T + row] = vs;
    }
}

extern "C" void kernel_launch(void* const* d_in, const int* in_sizes, int n_in,
                              void* d_out, int out_size, void* d_ws,
                              size_t ws_size, hipStream_t stream) {
    const float* E = (const float*)d_in[0];
    const float* WQp = (const float*)d_in[1];
    const float* WKp = (const float*)d_in[2];
    const float* WVop = (const float*)d_in[3];
    const float* WVarg = (const float*)d_in[4];
    const float* WQs = (const float*)d_in[5];
    const float* WKs = (const float*)d_in[6];
    const float* WVs = (const float*)d_in[7];
    float* out = (float*)d_out;

    float* wsf = (float*)d_ws;
    float* pv = wsf;
    float2* Kg = (float2*)(wsf + 2 * T * NCH);
    float2* Qg = (float2*)(wsf + 2 * T * NCH + 4 * T);

    proj_qk<<<T / 256, 256, 0, stream>>>(E, WQp, WKp, WQs, WKs, Qg, Kg);

    dim3 gB(RBLK, NCH, 2);
    maxscan<<<gB, 256, 0, stream>>>(Qg, Kg, pv);

    finalize<<<(2 * T) / 4, 256, 0, stream>>>(E, WVop, WVarg, WVs, pv, Qg, Kg,
                                              out);
}